// Round 1
// baseline (254.676 us; speedup 1.0000x reference)
//
#include <hip/hip_runtime.h>

#define E_EDGES 131072
// Layer dims: in {2048,4096,4096} -> out {4096,4096,1024}, batch 1024.
// Strategy: keep activations transposed (feature-major, [feat][1024]) so the
// per-edge batch-row read is coalesced. Build CSR-by-dst on device each call,
// then SpMM is a pure gather (no atomics in the hot loop).

__global__ void transpose_kernel(const float* __restrict__ in, float* __restrict__ out,
                                 int R, int C) {
  __shared__ float tile[32][33];
  int c0 = blockIdx.x << 5, r0 = blockIdx.y << 5;
  int tx = threadIdx.x, ty = threadIdx.y;  // 32 x 8
#pragma unroll
  for (int i = 0; i < 32; i += 8)
    tile[ty + i][tx] = in[(size_t)(r0 + ty + i) * C + (c0 + tx)];
  __syncthreads();
#pragma unroll
  for (int i = 0; i < 32; i += 8)
    out[(size_t)(c0 + ty + i) * R + (r0 + tx)] = tile[tx][ty + i];
}

// Histogram of dst for all 3 layers into cnt[3][4096]. Grid covers 3*E threads.
__global__ void hist3_kernel(const int* __restrict__ d0, const int* __restrict__ d1,
                             const int* __restrict__ d2, int* __restrict__ cnt) {
  int i = blockIdx.x * blockDim.x + threadIdx.x;
  int l = i / E_EDGES, e = i - l * E_EDGES;  // l uniform per block (E % 256 == 0)
  const int* dp = (l == 0) ? d0 : (l == 1) ? d1 : d2;
  atomicAdd(&cnt[(l << 12) + dp[e]], 1);
}

// Exclusive scan per layer (blockIdx = layer). n = 4096,4096,1024.
// Writes rowptr[l][0..n] and resets cnt (reused as scatter cursor) to row starts.
__global__ void scan3_kernel(int* __restrict__ cnt, int* __restrict__ rowptr) {
  int l = blockIdx.x;
  int n = (l == 2) ? 1024 : 4096;
  int* c = cnt + (l << 12);
  int* rp = rowptr + l * 4104;
  int t = threadIdx.x;  // 1024 threads
  int k = n >> 10;      // 4 or 1 elements per thread
  __shared__ int sums[1024];
  int vals[4];
  int local = 0;
  for (int i = 0; i < k; ++i) { vals[i] = c[t * k + i]; local += vals[i]; }
  sums[t] = local;
  __syncthreads();
  for (int off = 1; off < 1024; off <<= 1) {
    int v = sums[t];
    int a = (t >= off) ? sums[t - off] : 0;
    __syncthreads();
    sums[t] = v + a;
    __syncthreads();
  }
  int run = sums[t] - local;  // exclusive prefix of this thread's chunk
  for (int i = 0; i < k; ++i) { int v = vals[i]; rp[t * k + i] = run; c[t * k + i] = run; run += v; }
  if (t == 1023) rp[n] = run;  // == E
}

// Scatter edges into CSR order: edges_sorted[l][pos] = {src, bits(w)}.
__global__ void scatter3_kernel(const int* __restrict__ s0p, const int* __restrict__ d0p, const float* __restrict__ w0p,
                                const int* __restrict__ s1p, const int* __restrict__ d1p, const float* __restrict__ w1p,
                                const int* __restrict__ s2p, const int* __restrict__ d2p, const float* __restrict__ w2p,
                                int* __restrict__ cursor, int2* __restrict__ edges) {
  int i = blockIdx.x * blockDim.x + threadIdx.x;
  int l = i / E_EDGES, e = i - l * E_EDGES;
  const int* sp = (l == 0) ? s0p : (l == 1) ? s1p : s2p;
  const int* dp = (l == 0) ? d0p : (l == 1) ? d1p : d2p;
  const float* wp = (l == 0) ? w0p : (l == 1) ? w1p : w2p;
  int d = dp[e];
  int pos = atomicAdd(&cursor[(l << 12) + d], 1);
  edges[l * E_EDGES + pos] = make_int2(sp[e], __float_as_int(wp[e]));
}

// SpMM gather: block = (dst row d, 128-col batch chunk c). c = blockIdx & 7 so
// chunk c lands on XCD c (round-robin dispatch) -> each XCD's hT slice is 2 MB,
// L2-resident, and next layer's reads of this layer's writes stay on-XCD.
__global__ void __launch_bounds__(128) spmm_kernel(const float* __restrict__ hT,
                                                   const int2* __restrict__ edges,
                                                   const int* __restrict__ rowptr,
                                                   const float* __restrict__ bias,
                                                   float* __restrict__ outT) {
  int c = blockIdx.x & 7;
  int d = blockIdx.x >> 3;
  int col = (c << 7) + threadIdx.x;
  int s0 = rowptr[d], s1 = rowptr[d + 1];
  float acc0 = 0.f, acc1 = 0.f;
  int e = s0;
  for (; e + 1 < s1; e += 2) {
    int2 p0 = edges[e];
    int2 p1 = edges[e + 1];
    acc0 = fmaf(__int_as_float(p0.y), hT[((size_t)p0.x << 10) + col], acc0);
    acc1 = fmaf(__int_as_float(p1.y), hT[((size_t)p1.x << 10) + col], acc1);
  }
  if (e < s1) {
    int2 p = edges[e];
    acc0 = fmaf(__int_as_float(p.y), hT[((size_t)p.x << 10) + col], acc0);
  }
  float r = acc0 + acc1 + bias[d];
  outT[((size_t)d << 10) + col] = fmaxf(r, 0.f);
}

extern "C" void kernel_launch(void* const* d_in, const int* in_sizes, int n_in,
                              void* d_out, int out_size, void* d_ws, size_t ws_size,
                              hipStream_t stream) {
  const float* x = (const float*)d_in[0];
  const int* src[3]    = {(const int*)d_in[1], (const int*)d_in[5], (const int*)d_in[9]};
  const int* dst[3]    = {(const int*)d_in[2], (const int*)d_in[6], (const int*)d_in[10]};
  const float* w[3]    = {(const float*)d_in[3], (const float*)d_in[7], (const float*)d_in[11]};
  const float* bias[3] = {(const float*)d_in[4], (const float*)d_in[8], (const float*)d_in[12]};
  float* out = (float*)d_out;

  // Workspace layout (needs ~35.2 MB):
  //   buf0 @ 0        : 16 MB  (activation ping)
  //   buf1 @ 16 MB    : 16 MB  (activation pong)
  //   cnt  @ 32 MB    : 3*4096 ints (histogram, then scatter cursor)
  //   rowptr @ +64 KB : 3*4104 ints
  //   edges @ +192 KB : 3*E int2 (CSR-sorted {src, w})
  char* ws = (char*)d_ws;
  float* buf0  = (float*)(ws);
  float* buf1  = (float*)(ws + (16u << 20));
  int*   cnt   = (int*)(ws + (32u << 20));
  int*   rowptr= (int*)(ws + (32u << 20) + (64u << 10));
  int2*  edges = (int2*)(ws + (32u << 20) + (192u << 10));

  hipMemsetAsync(cnt, 0, 3 * 4096 * sizeof(int), stream);

  dim3 tb(32, 8);
  // x [1024][2048] -> buf0 = xT [2048][1024]
  transpose_kernel<<<dim3(2048 / 32, 1024 / 32), tb, 0, stream>>>(x, buf0, 1024, 2048);

  hist3_kernel<<<(3 * E_EDGES) / 256, 256, 0, stream>>>(dst[0], dst[1], dst[2], cnt);
  scan3_kernel<<<3, 1024, 0, stream>>>(cnt, rowptr);
  scatter3_kernel<<<(3 * E_EDGES) / 256, 256, 0, stream>>>(
      src[0], dst[0], w[0], src[1], dst[1], w[1], src[2], dst[2], w[2], cnt, edges);

  // layer 0: buf0 (2048x1024) -> buf1 (4096x1024)
  spmm_kernel<<<4096 * 8, 128, 0, stream>>>(buf0, edges, rowptr, bias[0], buf1);
  // layer 1: buf1 -> buf0 (4096x1024)
  spmm_kernel<<<4096 * 8, 128, 0, stream>>>(buf1, edges + E_EDGES, rowptr + 4104, bias[1], buf0);
  // layer 2: buf0 -> buf1 (1024x1024, outT)
  spmm_kernel<<<1024 * 8, 128, 0, stream>>>(buf0, edges + 2 * E_EDGES, rowptr + 2 * 4104, bias[2], buf1);

  // outT [1024 dst][1024 batch] -> d_out [batch][dst]
  transpose_kernel<<<dim3(1024 / 32, 1024 / 32), tb, 0, stream>>>(buf1, out, 1024, 1024);
}

// Round 2
// 212.566 us; speedup vs baseline: 1.1981x; 1.1981x over previous
//
#include <hip/hip_runtime.h>

#define E_EDGES 131072
// Layer dims: in {2048,4096,4096} -> out {4096,4096,1024}, batch 1024.
// Activations kept feature-major (hT[feat][1024]) so per-edge batch reads are
// coalesced. CSR-by-dst built on device each call; rows PADDED to a multiple
// of 8 edges (zero-weight pads) so the SpMM inner loop is an aligned int4
// stream with a software-pipelined 8-edge unroll (8 gathers in flight).

// Padded edge capacity per layer: E + 7*nrows.
#define EPAD01 159744   // layers 0,1 (4096 rows)
#define EPAD2  138240   // layer 2  (1024 rows)

__global__ void transpose_kernel(const float* __restrict__ in, float* __restrict__ out,
                                 int R, int C) {
  __shared__ float tile[32][33];
  int c0 = blockIdx.x << 5, r0 = blockIdx.y << 5;
  int tx = threadIdx.x, ty = threadIdx.y;  // 32 x 8
#pragma unroll
  for (int i = 0; i < 32; i += 8)
    tile[ty + i][tx] = in[(size_t)(r0 + ty + i) * C + (c0 + tx)];
  __syncthreads();
#pragma unroll
  for (int i = 0; i < 32; i += 8)
    out[(size_t)(c0 + ty + i) * R + (r0 + tx)] = tile[tx][ty + i];
}

// Histogram of dst for all 3 layers into cnt[3][4096].
__global__ void hist3_kernel(const int* __restrict__ d0, const int* __restrict__ d1,
                             const int* __restrict__ d2, int* __restrict__ cnt) {
  int i = blockIdx.x * blockDim.x + threadIdx.x;
  int l = i / E_EDGES, e = i - l * E_EDGES;  // l uniform per block
  const int* dp = (l == 0) ? d0 : (l == 1) ? d1 : d2;
  atomicAdd(&cnt[(l << 12) + dp[e]], 1);
}

// Exclusive scan of PADDED counts per layer (blockIdx = layer).
// rowptr gets padded row starts; cnt is reset to row starts (scatter cursor).
__global__ void scan3_kernel(int* __restrict__ cnt, int* __restrict__ rowptr) {
  int l = blockIdx.x;
  int n = (l == 2) ? 1024 : 4096;
  int* c = cnt + (l << 12);
  int* rp = rowptr + l * 4104;
  int t = threadIdx.x;  // 1024 threads
  int k = n >> 10;      // 4 or 1 elements per thread
  __shared__ int sums[1024];
  int vals[4];
  int local = 0;
  for (int i = 0; i < k; ++i) {
    int v = (c[t * k + i] + 7) & 0x7ffffff8;  // pad row to multiple of 8
    vals[i] = v; local += v;
  }
  sums[t] = local;
  __syncthreads();
  for (int off = 1; off < 1024; off <<= 1) {
    int v = sums[t];
    int a = (t >= off) ? sums[t - off] : 0;
    __syncthreads();
    sums[t] = v + a;
    __syncthreads();
  }
  int run = sums[t] - local;
  for (int i = 0; i < k; ++i) { int v = vals[i]; rp[t * k + i] = run; c[t * k + i] = run; run += v; }
  if (t == 1023) rp[n] = run;
}

// Scatter edges into padded CSR slots: edges[l_off + pos] = {src, bits(w)}.
// Pad slots stay {0, 0.0f} from the memset -> contribute nothing.
__global__ void scatter3_kernel(const int* __restrict__ s0p, const int* __restrict__ d0p, const float* __restrict__ w0p,
                                const int* __restrict__ s1p, const int* __restrict__ d1p, const float* __restrict__ w1p,
                                const int* __restrict__ s2p, const int* __restrict__ d2p, const float* __restrict__ w2p,
                                int* __restrict__ cursor, int2* __restrict__ edges) {
  int i = blockIdx.x * blockDim.x + threadIdx.x;
  int l = i / E_EDGES, e = i - l * E_EDGES;
  const int* sp = (l == 0) ? s0p : (l == 1) ? s1p : s2p;
  const int* dp = (l == 0) ? d0p : (l == 1) ? d1p : d2p;
  const float* wp = (l == 0) ? w0p : (l == 1) ? w1p : w2p;
  int off = (l == 0) ? 0 : (l == 1) ? EPAD01 : 2 * EPAD01;
  int d = dp[e];
  int pos = atomicAdd(&cursor[(l << 12) + d], 1);
  edges[off + pos] = make_int2(sp[e], __float_as_int(wp[e]));
}

// SpMM gather: block = (dst row d, 128-col batch chunk c). c = blockIdx & 7 so
// chunk c lands on XCD c -> each XCD's hT slice is 2 MB, L2-resident.
// Rows are multiples of 8 edges; pipeline: prefetch next 8 edges (2x int4x2)
// while 8 independent gathers for the current 8 edges are outstanding.
__global__ void __launch_bounds__(128) spmm_kernel(const float* __restrict__ hT,
                                                   const int2* __restrict__ edges,
                                                   const int* __restrict__ rowptr,
                                                   const float* __restrict__ bias,
                                                   float* __restrict__ outT) {
  int c = blockIdx.x & 7;
  int d = blockIdx.x >> 3;
  int col = (c << 7) + threadIdx.x;
  int s0 = rowptr[d], s1 = rowptr[d + 1];  // both multiples of 8
  const char* hb = (const char*)(hT + col);
  float acc0 = 0.f, acc1 = 0.f, acc2 = 0.f, acc3 = 0.f;
  const int4* ep = (const int4*)(edges + s0);      // 16B-aligned (s0 % 8 == 0)
  const int4* ep_end = (const int4*)(edges + s1);
  int4 q0, q1, q2, q3;
  if (ep < ep_end) { q0 = ep[0]; q1 = ep[1]; q2 = ep[2]; q3 = ep[3]; }
  while (ep < ep_end) {
    int4 p0 = q0, p1 = q1, p2 = q2, p3 = q3;
    ep += 4;
    if (ep < ep_end) { q0 = ep[0]; q1 = ep[1]; q2 = ep[2]; q3 = ep[3]; }
    float v0 = *(const float*)(hb + ((size_t)(unsigned)p0.x << 12));
    float v1 = *(const float*)(hb + ((size_t)(unsigned)p0.z << 12));
    float v2 = *(const float*)(hb + ((size_t)(unsigned)p1.x << 12));
    float v3 = *(const float*)(hb + ((size_t)(unsigned)p1.z << 12));
    float v4 = *(const float*)(hb + ((size_t)(unsigned)p2.x << 12));
    float v5 = *(const float*)(hb + ((size_t)(unsigned)p2.z << 12));
    float v6 = *(const float*)(hb + ((size_t)(unsigned)p3.x << 12));
    float v7 = *(const float*)(hb + ((size_t)(unsigned)p3.z << 12));
    acc0 = fmaf(__int_as_float(p0.y), v0, acc0);
    acc1 = fmaf(__int_as_float(p0.w), v1, acc1);
    acc2 = fmaf(__int_as_float(p1.y), v2, acc2);
    acc3 = fmaf(__int_as_float(p1.w), v3, acc3);
    acc0 = fmaf(__int_as_float(p2.y), v4, acc0);
    acc1 = fmaf(__int_as_float(p2.w), v5, acc1);
    acc2 = fmaf(__int_as_float(p3.y), v6, acc2);
    acc3 = fmaf(__int_as_float(p3.w), v7, acc3);
  }
  float r = (acc0 + acc1) + (acc2 + acc3) + bias[d];
  outT[((size_t)d << 10) + col] = fmaxf(r, 0.f);
}

extern "C" void kernel_launch(void* const* d_in, const int* in_sizes, int n_in,
                              void* d_out, int out_size, void* d_ws, size_t ws_size,
                              hipStream_t stream) {
  const float* x = (const float*)d_in[0];
  const int* src[3]    = {(const int*)d_in[1], (const int*)d_in[5], (const int*)d_in[9]};
  const int* dst[3]    = {(const int*)d_in[2], (const int*)d_in[6], (const int*)d_in[10]};
  const float* w[3]    = {(const float*)d_in[3], (const float*)d_in[7], (const float*)d_in[11]};
  const float* bias[3] = {(const float*)d_in[4], (const float*)d_in[8], (const float*)d_in[12]};
  float* out = (float*)d_out;

  // Workspace layout (~35.6 MB):
  //   buf0 @ 0      : 16 MB  (xT, later h2T)
  //   buf1 @ 16 MB  : 16 MB  (h1T, later outT)
  //   cnt  @ 32 MB  : 3*4096 ints (histogram -> scatter cursor)   \ one
  //   edges@ +48 KB : (2*EPAD01 + EPAD2) int2, padded CSR          / memset
  //   rowptr@ after : 3*4104 ints
  char* ws = (char*)d_ws;
  float* buf0   = (float*)(ws);
  float* buf1   = (float*)(ws + (16u << 20));
  int*   cnt    = (int*)(ws + (32u << 20));
  int2*  edges  = (int2*)(ws + (32u << 20) + 49152u);
  size_t edges_bytes = (size_t)(2 * EPAD01 + EPAD2) * sizeof(int2);
  int*   rowptr = (int*)((char*)edges + edges_bytes);

  // Zero cnt + edges in one contiguous memset (pad slots must be {0, 0.0f}).
  hipMemsetAsync(cnt, 0, 49152u + edges_bytes, stream);

  dim3 tb(32, 8);
  // x [1024][2048] -> buf0 = xT [2048][1024]
  transpose_kernel<<<dim3(2048 / 32, 1024 / 32), tb, 0, stream>>>(x, buf0, 1024, 2048);

  hist3_kernel<<<(3 * E_EDGES) / 256, 256, 0, stream>>>(dst[0], dst[1], dst[2], cnt);
  scan3_kernel<<<3, 1024, 0, stream>>>(cnt, rowptr);
  scatter3_kernel<<<(3 * E_EDGES) / 256, 256, 0, stream>>>(
      src[0], dst[0], w[0], src[1], dst[1], w[1], src[2], dst[2], w[2], cnt, edges);

  // layer 0: buf0 (2048x1024) -> buf1 (4096x1024)
  spmm_kernel<<<4096 * 8, 128, 0, stream>>>(buf0, edges, rowptr, bias[0], buf1);
  // layer 1: buf1 -> buf0 (4096x1024)
  spmm_kernel<<<4096 * 8, 128, 0, stream>>>(buf1, edges + EPAD01, rowptr + 4104, bias[1], buf0);
  // layer 2: buf0 -> buf1 (1024x1024, outT)
  spmm_kernel<<<1024 * 8, 128, 0, stream>>>(buf0, edges + 2 * EPAD01, rowptr + 2 * 4104, bias[2], buf1);

  // outT [1024 dst][1024 batch] -> d_out [batch][dst]
  transpose_kernel<<<dim3(1024 / 32, 1024 / 32), tb, 0, stream>>>(buf1, out, 1024, 1024);
}